// Round 17
// baseline (114.285 us; speedup 1.0000x reference)
//
#include <hip/hip_runtime.h>

// ---------------------------------------------------------------------------
// MultiHeadAttention with relational-adjacency mask, MI355X (gfx950)
// B=32, L=512, DIM=256, NH=4, HD=64.  SCALE = 8.
//
// Pipeline:
//  prep            : x,w_qkv -> bf16; w_proj -> [hi|hi|lo]; adj -> row bitsets
//  transpose_bits  : ballot bit-transpose -> colraw + maskA[1]
//  mask23p         : maskA[2,3] with chunk-parallel OR-reduce (256 blocks)
//  gemm_qkv        : qkv = x @ w_qkv^T via global_load_lds staging, scatter
//  attn            : barrier-free flash attn v8 — no max-tracking, gload_lds
//                    staging, wave-private LDS P-relayout, mask prefetch
//  gemm_out        : out = ctx @ wproj_aug^T (global_load_lds, k>=512 wrap)
// ---------------------------------------------------------------------------

typedef unsigned long long u64;
typedef unsigned short u16;
typedef short bf16x8 __attribute__((ext_vector_type(8)));
typedef float f32x4 __attribute__((ext_vector_type(4)));

#define MFMA16(a, b, c) __builtin_amdgcn_mfma_f32_16x16x32_bf16((a), (b), (c), 0, 0, 0)

__device__ __forceinline__ unsigned f2bf(float f) {           // f32 -> bf16 (RNE)
  unsigned u = __float_as_uint(f);
  return (u + 0x7FFFu + ((u >> 16) & 1u)) >> 16;
}
__device__ __forceinline__ float bf2f(unsigned b) { return __uint_as_float(b << 16); }

// v_cvt_pk_bf16_f32: dst.lo = bf16(lo), dst.hi = bf16(hi)  (RNE)
__device__ __forceinline__ unsigned cvtpk(float lo, float hi) {
  unsigned r;
  asm("v_cvt_pk_bf16_f32 %0, %1, %2" : "=v"(r) : "v"(lo), "v"(hi));
  return r;
}

// async global -> LDS, 16B per lane.  LDS dest = wave-uniform base + lane*16
// (linear); swizzle is applied on the per-lane GLOBAL source + on LDS reads.
__device__ __forceinline__ void gload16(const u16* src, u16* ldsDst) {
  __builtin_amdgcn_global_load_lds(
      (const __attribute__((address_space(1))) void*)src,
      (__attribute__((address_space(3))) void*)ldsDst, 16, 0, 0);
}

// XOR bank swizzles: flip 16B-chunk bits (3..5 of elem offset) with row&7.
__device__ __forceinline__ int swzE(int row, int e) {
  return row * 64 + (e ^ ((row & 7) << 3));
}
__device__ __forceinline__ int swzV(int row, int c) {
  return row * 512 + (c ^ ((row & 7) << 3));
}

// ---- workspace layout (bytes) ---------------------------------------------
#define OFF_XB    ((size_t)0)          // x bf16        [16384][256]   8,388,608
#define OFF_WQKV  ((size_t)8388608)    // w_qkv bf16    [768][256]       393,216
#define OFF_WPA   ((size_t)8781824)    // w_proj aug    [256][768]       393,216
#define OFF_QB    ((size_t)9175040)    // q bf16        [32][4][512][64] 8,388,608
#define OFF_KB    ((size_t)17563648)   // k bf16        [32][4][512][64] 8,388,608
#define OFF_VTB   ((size_t)25952256)   // vT bf16       [32][4][64][512] 8,388,608
#define OFF_CTXA  ((size_t)34340864)   // ctx [hi|lo]   [16384][512]    16,777,216
#define OFF_ROWR  ((size_t)51118080)   // row bitsets   [32][512][8]u64  1,048,576
#define OFF_COLR  ((size_t)52166656)   // col bitsets   [32][512][8]u64  1,048,576
#define OFF_MASK  ((size_t)53215232)   // maskA[4][32][512][8]u64        4,194,304
// total 57,409,536 B (~54.8 MB)

// ---------------------------------------------------------------------------
// Fused prep: blk<1024 x->bf16; 1024..1071 w_qkv->bf16; 1072..1199 w_proj aug;
// 1200..3247 adj bitpack (+maskA0).  All 512-thread blocks.
__global__ __launch_bounds__(512) void prep(const float* __restrict__ x, u16* __restrict__ xb,
                                            const float* __restrict__ wqkv, u16* __restrict__ wqkvb,
                                            const float* __restrict__ wp, u16* __restrict__ wpa,
                                            const int* __restrict__ adj, u64* __restrict__ rowraw,
                                            u64* __restrict__ maskA0) {
  int blk = blockIdx.x;
  if (blk < 1072) {
    const float* src = (blk < 1024) ? x : wqkv;
    u16* dst = (blk < 1024) ? xb : wqkvb;
    int bb = (blk < 1024) ? blk : (blk - 1024);
    size_t i = ((size_t)bb * 512 + threadIdx.x) * 8;
    float4 a = *(const float4*)(src + i);
    float4 c = *(const float4*)(src + i + 4);
    uint4 o;
    o.x = f2bf(a.x) | (f2bf(a.y) << 16);
    o.y = f2bf(a.z) | (f2bf(a.w) << 16);
    o.z = f2bf(c.x) | (f2bf(c.y) << 16);
    o.w = f2bf(c.z) | (f2bf(c.w) << 16);
    *(uint4*)(dst + i) = o;
  } else if (blk < 1200) {
    int idx = (blk - 1072) * 512 + threadIdx.x;   // 0..65535
    int n = idx >> 8, k = idx & 255;
    float v = wp[idx];
    unsigned hi = f2bf(v);
    unsigned lo = f2bf(v - bf2f(hi));
    size_t base = (size_t)n * 768;
    wpa[base + k]       = (u16)hi;
    wpa[base + 256 + k] = (u16)hi;
    wpa[base + 512 + k] = (u16)lo;
  } else {
    int blk2 = blk - 1200;                // 64 blocks per batch b
    int b = blk2 >> 6, r0 = (blk2 & 63) * 8;
    int wave = threadIdx.x >> 6, lane = threadIdx.x & 63;
    #pragma unroll
    for (int rr = 0; rr < 8; ++rr) {
      int row = r0 + rr;
      int v = adj[((size_t)b * 512 + row) * 512 + wave * 64 + lane];
      u64 bal = __ballot(v == 1 || v >= 9);
      if (lane == 0) {
        size_t o = ((size_t)b * 512 + row) * 8 + wave;
        rowraw[o] = bal;
        maskA0[o] = bal | (((row >> 6) == wave) ? (1ull << (row & 63)) : 0ull);
      }
    }
  }
}

// ---------------------------------------------------------------------------
// row bitsets -> col bitsets via ballot bit-transpose.  grid 32 x 512 (8 waves).
__global__ __launch_bounds__(512) void transpose_bits(const u64* __restrict__ rowraw,
                                                      u64* __restrict__ colraw,
                                                      u64* __restrict__ maskA1) {
  __shared__ u64 btr[8 * 512];   // [word][row]
  int b = blockIdx.x, tid = threadIdx.x;
  {
    const u64* src = rowraw + (size_t)b * 4096 + (size_t)tid * 8;
    u64 r[8];
    #pragma unroll
    for (int w = 0; w < 8; ++w) r[w] = src[w];
    #pragma unroll
    for (int w = 0; w < 8; ++w) btr[w * 512 + tid] = r[w];
  }
  __syncthreads();
  int w = tid >> 6, lane = tid & 63;    // wave w handles cols w*64 .. w*64+63
  u64 words[8];
  #pragma unroll
  for (int wd = 0; wd < 8; ++wd) {
    u64 word = btr[w * 512 + wd * 64 + lane];   // rowraw[row=wd*64+lane], word w
    u64 mine = 0;
    #pragma unroll 1
    for (int c = 0; c < 64; ++c) {
      u64 bal = __ballot((word >> c) & 1ull);   // bit t = a[wd*64+t][w*64+c]
      if (lane == c) mine = bal;
    }
    words[wd] = mine;
  }
  int col = w * 64 + lane;
  u64* crow = colraw + (size_t)b * 4096 + (size_t)col * 8;
  u64* mrow = maskA1 + (size_t)b * 4096 + (size_t)col * 8;
  #pragma unroll
  for (int wd = 0; wd < 8; ++wd) crow[wd] = words[wd];
  words[w] |= (1ull << lane);                    // eye: col diag bit
  #pragma unroll
  for (int wd = 0; wd < 8; ++wd) mrow[wd] = words[wd];
}

// ---------------------------------------------------------------------------
// mask23p: m2 = (aT@a != 0)|eye, m3 = (a@aT != 0)|eye.  grid (32 b, 8 qc) x 512.
// Thread (q_local = tid>>3, wg = tid&7) accumulates the OR over its 64-column
// chunk c in [wg*64, wg*64+64); partials combined via 3-round shfl_xor within
// the aligned 8-lane wg-group.  LDS staged with +1 u64 pad per 64-c chunk so
// the 8 chunk-broadcast reads hit 16 distinct banks (conflict-free).
__global__ __launch_bounds__(512) void mask23p(const u64* __restrict__ rowraw,
                                               const u64* __restrict__ colraw,
                                               u64* __restrict__ maskA2,
                                               u64* __restrict__ maskA3) {
  __shared__ u64 rb[4104];   // idx(c,w) = c*8 + w + (c>>6)
  __shared__ u64 cb[4104];
  const int b = blockIdx.x, qc = blockIdx.y, tid = threadIdx.x;
  for (int i = tid; i < 4096; i += 512) {
    int li = i + (i >> 9);
    rb[li] = rowraw[(size_t)b * 4096 + i];
    cb[li] = colraw[(size_t)b * 4096 + i];
  }
  __syncthreads();

  const int ql = tid >> 3, wg = tid & 7;
  const int q = qc * 64 + ql;
  const u64 myrow_w = rb[q * 8 + wg + (q >> 6)];   // word wg of rowraw[q]
  const u64 mycol_w = cb[q * 8 + wg + (q >> 6)];   // word wg of colraw[q]

  u64 a2[8] = {0, 0, 0, 0, 0, 0, 0, 0}, a3[8] = {0, 0, 0, 0, 0, 0, 0, 0};
  #pragma unroll 4
  for (int cc = 0; cc < 64; ++cc) {
    int base = (wg * 64 + cc) * 8 + wg;            // idx(c, 0), c = wg*64+cc
    u64 p3 = 0ull - ((myrow_w >> cc) & 1ull);
    u64 p2 = 0ull - ((mycol_w >> cc) & 1ull);
    #pragma unroll
    for (int w = 0; w < 8; ++w) {
      a3[w] |= cb[base + w] & p3;                  // colraw[c]
      a2[w] |= rb[base + w] & p2;                  // rowraw[c]
    }
  }

  // combine the 8 chunk-partials (aligned 8-lane group) via butterfly
  #pragma unroll
  for (int off = 1; off < 8; off <<= 1)
    #pragma unroll
    for (int w = 0; w < 8; ++w) {
      a2[w] |= __shfl_xor(a2[w], off);
      a3[w] |= __shfl_xor(a3[w], off);
    }

  // thread stores word wg of its q (coalesced across the 8-lane group)
  u64 eye = ((q >> 6) == wg) ? (1ull << (q & 63)) : 0ull;
  size_t o = (size_t)b * 4096 + (size_t)q * 8 + wg;
  maskA2[o] = a2[wg] | eye;
  maskA3[o] = a3[wg] | eye;
}

// ---------------------------------------------------------------------------
// QKV GEMM: qkv = x @ w_qkv^T.  128x128 tile, BK=64, 4 k-steps, 4 waves 2x2.
// global_load_lds width 16, linear LDS dest, inverse-swizzled global source.
__global__ __launch_bounds__(256) void gemm_qkv(const u16* __restrict__ A,
                                                const u16* __restrict__ Bw,
                                                u16* __restrict__ o_q, u16* __restrict__ o_k,
                                                u16* __restrict__ o_v) {
  __shared__ u16 As[128 * 64];
  __shared__ u16 Bs[128 * 64];
  const int lin = blockIdx.x;
  const int logical = (lin & 7) * 96 + (lin >> 3);   // 768%8==0 -> bijective
  const int m0 = (logical / 6) * 128, n0 = (logical % 6) * 128;
  const int tid = threadIdx.x;
  const int lane = tid & 63, wid = tid >> 6;
  const int lg = lane >> 4, lc = lane & 15;
  const int wm = wid >> 1, wn = wid & 1;
  f32x4 acc[4][4] = {};

  const int srow = lane >> 3;                        // 0..7 within 8-row slab
  const int schunk = ((lane & 7) ^ srow) * 8;        // inverse swizzle
  #define STAGE_QKV(ks)                                                        \
    {                                                                          \
      int kk0 = (ks) * 64;                                                     \
      _Pragma("unroll")                                                        \
      for (int j = 0; j < 4; ++j) {                                            \
        int slab = wid * 4 + j;                                                \
        int r = slab * 8 + srow;                                               \
        gload16(A + (size_t)(m0 + r) * 256 + kk0 + schunk, &As[slab * 512]);   \
        gload16(Bw + (size_t)(n0 + r) * 256 + kk0 + schunk, &Bs[slab * 512]);  \
      }                                                                        \
    }

  STAGE_QKV(0);
  for (int ks = 0; ks < 4; ++ks) {
    __syncthreads();                   // vmcnt drained -> tile ks in LDS
    bf16x8 af[2][4], bf[2][4];
    #pragma unroll
    for (int kk = 0; kk < 2; ++kk)
      #pragma unroll
      for (int mi = 0; mi < 4; ++mi) {
        af[kk][mi] = *(const bf16x8*)&As[swzE(wm * 64 + mi * 16 + lc, kk * 32 + lg * 8)];
        bf[kk][mi] = *(const bf16x8*)&Bs[swzE(wn * 64 + mi * 16 + lc, kk * 32 + lg * 8)];
      }
    __syncthreads();                   // all waves done reading LDS
    if (ks < 3) STAGE_QKV(ks + 1);     // async loads overlap the MFMA block
    #pragma unroll
    for (int kk = 0; kk < 2; ++kk)
      #pragma unroll
      for (int mi = 0; mi < 4; ++mi)
        #pragma unroll
        for (int ni = 0; ni < 4; ++ni)
          acc[mi][ni] = MFMA16(af[kk][mi], bf[kk][ni], acc[mi][ni]);
  }
  #undef STAGE_QKV

  // scatter epilogue -> q[b][h][l][d], k[b][h][l][d], vT[b][h][d][l]
  #pragma unroll
  for (int mi = 0; mi < 4; ++mi) {
    int mbase = m0 + wm * 64 + mi * 16 + lg * 4;
    int bb = mbase >> 9, l = mbase & 511;
    #pragma unroll
    for (int ni = 0; ni < 4; ++ni) {
      int n = n0 + wn * 64 + ni * 16 + lc;
      if (n < 512) {   // uniform within each 16-lane group
        u16* dst = (n < 256) ? o_q : o_k;
        int c = n & 255, hh = c >> 6, dd = c & 63;
        size_t base = (((size_t)bb * 4 + hh) * 512 + l) * 64 + dd;
        #pragma unroll
        for (int r = 0; r < 4; ++r) dst[base + (size_t)r * 64] = (u16)f2bf(acc[mi][ni][r]);
      } else {         // V transposed per head: vT[b][h][d][l]
        int c = n - 512, hh = c >> 6, dd = c & 63;
        ushort4 pk;
        pk.x = (u16)f2bf(acc[mi][ni][0]); pk.y = (u16)f2bf(acc[mi][ni][1]);
        pk.z = (u16)f2bf(acc[mi][ni][2]); pk.w = (u16)f2bf(acc[mi][ni][3]);
        *(ushort4*)&o_v[(((size_t)bb * 4 + hh) * 64 + dd) * 512 + l] = pk;
      }
    }
  }
}

// ---------------------------------------------------------------------------
// Out-projection GEMM: 64x128 tile, BK=64, 12 k-steps, grid 512, XCD-chunked.
__global__ __launch_bounds__(256) void gemm_out(const u16* __restrict__ A,
                                                const u16* __restrict__ Bw,
                                                float* __restrict__ o_f) {
  __shared__ u16 As[64 * 64];
  __shared__ u16 Bs[128 * 64];
  const int lin = blockIdx.x;
  const int logical = (lin & 7) * 64 + (lin >> 3);   // 512%8==0 -> bijective
  const int m0 = (logical >> 1) * 64, n0 = (logical & 1) * 128;
  const int tid = threadIdx.x;
  const int lane = tid & 63, wid = tid >> 6;
  const int lg = lane >> 4, lc = lane & 15;
  const int wm = wid >> 1, wn = wid & 1;
  f32x4 acc[2][4] = {};

  const int srow = lane >> 3;
  const int schunk = ((lane & 7) ^ srow) * 8;
  #define STAGE_OUT(ks)                                                        \
    {                                                                          \
      int k0 = (ks) * 64;                                                      \
      int ka0 = (k0 >= 512) ? k0 - 512 : k0;                                   \
      _Pragma("unroll")                                                        \
      for (int j = 0; j < 2; ++j) {                                            \
        int slab = wid * 2 + j;                                                \
        int r = slab * 8 + srow;                                               \
        gload16(A + (size_t)(m0 + r) * 512 + ka0 + schunk, &As[slab * 512]);   \
      }                                                                        \
      _Pragma("unroll")                                                        \
      for (int j = 0; j < 4; ++j) {                                            \
        int slab = wid * 4 + j;                                                \
        int r = slab * 8 + srow;                                               \
        gload16(Bw + (size_t)(n0 + r) * 768 + k0 + schunk, &Bs[slab * 512]);   \
      }                                                                        \
    }

  STAGE_OUT(0);
  for (int ks = 0; ks < 12; ++ks) {
    __syncthreads();
    bf16x8 af[2][2], bf[2][4];
    #pragma unroll
    for (int kk = 0; kk < 2; ++kk) {
      #pragma unroll
      for (int mi = 0; mi < 2; ++mi)
        af[kk][mi] = *(const bf16x8*)&As[swzE(wm * 32 + mi * 16 + lc, kk * 32 + lg * 8)];
      #pragma unroll
      for (int ni = 0; ni < 4; ++ni)
        bf[kk][ni] = *(const bf16x8*)&Bs[swzE(wn * 64 + ni * 16 + lc, kk * 32 + lg * 8)];
    }
    __syncthreads();
    if (ks < 11) STAGE_OUT(ks + 1);
    #pragma unroll
    for (int kk = 0; kk < 2; ++kk)
      #pragma unroll
      for (int mi = 0; mi < 2; ++mi)
        #pragma unroll
        for (int ni = 0; ni < 4; ++ni)
          acc[mi][ni] = MFMA16(af[kk][mi], bf[kk][ni], acc[mi][ni]);
  }
  #undef STAGE_OUT

  #pragma unroll
  for (int mi = 0; mi < 2; ++mi) {
    int mbase = m0 + wm * 32 + mi * 16 + lg * 4;
    #pragma unroll
    for (int ni = 0; ni < 4; ++ni) {
      int n = n0 + wn * 64 + ni * 16 + lc;
      #pragma unroll
      for (int r = 0; r < 4; ++r) o_f[(size_t)(mbase + r) * 256 + n] = acc[mi][ni][r];
    }
  }
}

// ---------------------------------------------------------------------------
// P-step v8: no max-tracking (shift-invariant; scores provably small).
// Masked -> 0.  Per-lane partial row-sum in lrun (reduced in epilogue).
// Relayout C/D -> A-frag through the wave-private LDS buffer PsW:
// 4 x ds_write_b64 (P^T[q=lc][k]) then 2 x ds_read_b128.  DS ops are
// per-wave in-order -> no barrier, and sequential A/B reuse is WAR-safe.
__device__ __forceinline__ void p_step(const f32x4 sT[4], u64 mw, int lane, u16* PsW,
                                       float& lrun, bf16x8& ap0, bf16x8& ap1) {
  const float SC = 0.125f * 1.4426950408889634f;   // /sqrt(64) * log2(e)
  const int lg = lane >> 4, lc = lane & 15;
  float p[4][4];
  float ps = 0.f;
  #pragma unroll
  for (int nf = 0; nf < 4; ++nf)
    #pragma unroll
    for (int r = 0; r < 4; ++r) {
      bool ok = (mw >> (nf * 16 + r)) & 1ull;
      float e = __builtin_amdgcn_exp2f(sT[nf][r] * SC);
      e = ok ? e : 0.f;
      p[nf][r] = e;
      ps += e;
    }
  lrun += ps;

  #pragma unroll
  for (int nf = 0; nf < 4; ++nf) {
    uint2 w2;
    w2.x = cvtpk(p[nf][0], p[nf][1]);
    w2.y = cvtpk(p[nf][2], p[nf][3]);
    *(uint2*)&PsW[swzE(lc, nf * 16 + lg * 4)] = w2;   // keys nf*16+lg*4+0..3
  }
  ap0 = *(const bf16x8*)&PsW[swzE(lc, lg * 8)];
  ap1 = *(const bf16x8*)&PsW[swzE(lc, lg * 8 + 32)];
}

// ---------------------------------------------------------------------------
// Flash attention v8 — barrier-free, dual q-group, no max-tracking.
// Grid 256 (XCD-chunked), block = 512 threads (8 waves), 256 q-rows/block.
// K/V staged via global_load_lds (inverse-swizzled source, linear LDS dest).
// LDS: 64 (K) + 64 (V) + 16 (Ps) = 144 KB -> 1 block/CU, 8 waves.
__global__ __launch_bounds__(512, 1) void attn(const u16* __restrict__ qb, const u16* __restrict__ kb,
                                               const u16* __restrict__ vtb, const u64* __restrict__ maskA,
                                               u16* __restrict__ ctxa) {
  __shared__ u16 Ks[512 * 64];   // 64 KB, swzE
  __shared__ u16 Vs[64 * 512];   // 64 KB, swzV
  __shared__ u16 Ps[8][16 * 64]; // 16 KB, wave-private P relayout buffers
  const int lin = blockIdx.x;
  const int logical = (lin & 7) * 32 + (lin >> 3);   // lin%8 = XCD; bijective
  const int bh = logical >> 1, half = logical & 1;
  const int b = bh >> 2, h = bh & 3;
  const int tid = threadIdx.x, lane = tid & 63, wid = tid >> 6;   // wid 0..7
  const int lg = lane >> 4, lc = lane & 15;

  // ---- stage K [512][64] and V^T [64][512] via global_load_lds ----
  {
    const u16* kgs = kb + (size_t)bh * 512 * 64;
    const u16* vgs = vtb + (size_t)bh * 64 * 512;
    const int srow = lane >> 3;                    // K: 8 rows/slab, 8 lanes/row
    const int schunk = ((lane & 7) ^ srow) * 8;    // inverse swzE
    #pragma unroll
    for (int j = 0; j < 8; ++j) {
      int slab = wid * 8 + j;                      // 64 slabs
      gload16(kgs + (size_t)(slab * 8 + srow) * 64 + schunk, &Ks[slab * 512]);
    }
    #pragma unroll
    for (int j = 0; j < 8; ++j) {
      int vr = wid * 8 + j;                        // 64 V rows, 1 row/wave-inst
      gload16(vgs + (size_t)vr * 512 + ((lane ^ (vr & 7)) * 8), &Vs[vr * 512]);
    }
  }

  // Q as B-frag (col = q = lc, inner = d): two 16-row groups per wave
  const int qrow0 = half * 256 + wid * 32;
  const u16* qgA = qb + ((size_t)bh * 512 + qrow0 + lc) * 64;
  const u16* qgB = qgA + 16 * 64;
  bf16x8 qA0 = *(const bf16x8*)(qgA + lg * 8);
  bf16x8 qA1 = *(const bf16x8*)(qgA + 32 + lg * 8);
  bf16x8 qB0 = *(const bf16x8*)(qgB + lg * 8);
  bf16x8 qB1 = *(const bf16x8*)(qgB + 32 + lg * 8);

  float lrunA = 0.f, lrunB = 0.f;
  f32x4 accoA[4] = {}, accoB[4] = {};
  const u64* mrowA = maskA + ((size_t)(h * 32 + b) * 512 + qrow0 + lc) * 8;
  const u64* mrowB = mrowA + 16 * 8;
  u16* PsW = Ps[wid];

  u64 mwA = mrowA[0], mwB = mrowB[0];   // mask prefetch depth-1

  __syncthreads();   // staging visible; the ONLY block-wide sync

  for (int kt = 0; kt < 8; ++kt) {
    u64 nmwA = (kt < 7) ? mrowA[kt + 1] : 0ull;   // prefetch next tile's masks
    u64 nmwB = (kt < 7) ? mrowB[kt + 1] : 0ull;

    f32x4 sA[4], sB[4];
    __builtin_amdgcn_s_setprio(1);
    #pragma unroll
    for (int nf = 0; nf < 4; ++nf) {
      bf16x8 ak0 = *(const bf16x8*)&Ks[swzE(kt * 64 + nf * 16 + lc, lg * 8)];
      bf16x8 ak1 = *(const bf16x8*)&Ks[swzE(kt * 64 + nf * 16 + lc, lg * 8 + 32)];
      f32x4 zA = {0.f, 0.f, 0.f, 0.f};
      zA = MFMA16(ak0, qA0, zA);
      zA = MFMA16(ak1, qA1, zA);
      sA[nf] = zA;
      f32x4 zB = {0.f, 0.f, 0.f, 0.f};
      zB = MFMA16(ak0, qB0, zB);
      zB = MFMA16(ak1, qB1, zB);
      sB[nf] = zB;
    }
    __builtin_amdgcn_s_setprio(0);

    bf16x8 apA0, apA1, apB0, apB1;
    p_step(sA, mwA >> (lg * 4), lane, PsW, lrunA, apA0, apA1);
    p_step(sB, mwB >> (lg * 4), lane, PsW, lrunB, apB0, apB1);

    __builtin_amdgcn_s_setprio(1);
    #pragma unroll
    for (int df = 0; df < 4; ++df) {
      bf16x8 bv0 = *(const bf16x8*)&Vs[swzV(df * 16 + lc, kt * 64 + lg * 8)];
      bf16x8 bv1 = *(const bf16x8*)&Vs[swzV(df * 16 + lc, kt * 64 + 32 + lg * 8)];
      accoA[df] = MFMA16(apA0, bv0, accoA[df]);
      accoA[df] = MFMA16(apA1, bv1, accoA[df]);
      accoB[df] = MFMA16(apB0, bv0, accoB[df]);
      accoB[df] = MFMA16(apB1, bv1, accoB[df]);
    }
    __builtin_amdgcn_s_setprio(0);

    mwA = nmwA;
    mwB = nmwB;
  }

  // epilogue: reduce per-lane partial sums across the 4 lane-groups, then
  // normalize.  r outer / df inner (write-combine friendly), both groups.
  lrunA += __shfl_xor(lrunA, 16);
  lrunA += __shfl_xor(lrunA, 32);
  lrunB += __shfl_xor(lrunB, 16);
  lrunB += __shfl_xor(lrunB, 32);
  float lrA[4], lrB[4];
  #pragma unroll
  for (int r = 0; r < 4; ++r) {
    lrA[r] = 1.0f / __shfl(lrunA, (lane & 48) | (lg * 4 + r));
    lrB[r] = 1.0f / __shfl(lrunB, (lane & 48) | (lg * 4 + r));
  }
  #pragma unroll
  for (int r = 0; r < 4; ++r) {
    int rowq = qrow0 + lg * 4 + r;
    size_t baseA = ((size_t)b * 512 + rowq) * 512;
    size_t baseB = ((size_t)b * 512 + rowq + 16) * 512;
    #pragma unroll
    for (int df = 0; df < 4; ++df) {
      int c = h * 64 + df * 16 + lc;
      float vA = accoA[df][r] * lrA[r];
      unsigned hiA = f2bf(vA);
      ctxa[baseA + c]       = (u16)hiA;
      ctxa[baseA + 256 + c] = (u16)f2bf(vA - bf2f(hiA));
      float vB = accoB[df][r] * lrB[r];
      unsigned hiB = f2bf(vB);
      ctxa[baseB + c]       = (u16)hiB;
      ctxa[baseB + 256 + c] = (u16)f2bf(vB - bf2f(hiB));
    }
  }
}

// ---------------------------------------------------------------------------
extern "C" void kernel_launch(void* const* d_in, const int* in_sizes, int n_in,
                              void* d_out, int out_size, void* d_ws, size_t ws_size,
                              hipStream_t stream) {
  const float* x     = (const float*)d_in[0];
  const int*   adj   = (const int*)d_in[1];
  const float* wqkv  = (const float*)d_in[2];
  const float* wproj = (const float*)d_in[3];
  char* ws = (char*)d_ws;
  u16* xb     = (u16*)(ws + OFF_XB);
  u16* wqkvb  = (u16*)(ws + OFF_WQKV);
  u16* wpa    = (u16*)(ws + OFF_WPA);
  u16* qb     = (u16*)(ws + OFF_QB);
  u16* kb     = (u16*)(ws + OFF_KB);
  u16* vtb    = (u16*)(ws + OFF_VTB);
  u16* ctxa   = (u16*)(ws + OFF_CTXA);
  u64* rowraw = (u64*)(ws + OFF_ROWR);
  u64* colraw = (u64*)(ws + OFF_COLR);
  u64* maskA  = (u64*)(ws + OFF_MASK);
  const size_t MSTRIDE = (size_t)32 * 512 * 8;   // u64 elems per head-mask

  prep<<<dim3(3248), 512, 0, stream>>>(x, xb, wqkv, wqkvb, wproj, wpa, adj, rowraw, maskA);
  transpose_bits<<<dim3(32), 512, 0, stream>>>(rowraw, colraw, maskA + MSTRIDE);
  mask23p<<<dim3(32, 8), 512, 0, stream>>>(rowraw, colraw, maskA + 2 * MSTRIDE, maskA + 3 * MSTRIDE);
  gemm_qkv<<<dim3(768), 256, 0, stream>>>(xb, wqkvb, qb, kb, vtb);
  attn<<<dim3(256), 512, 0, stream>>>(qb, kb, vtb, maskA, ctxa);
  gemm_out<<<dim3(512), 256, 0, stream>>>(ctxa, wpa, (float*)d_out);
}

// Round 18
// 107.279 us; speedup vs baseline: 1.0653x; 1.0653x over previous
//
#include <hip/hip_runtime.h>

// ---------------------------------------------------------------------------
// MultiHeadAttention with relational-adjacency mask, MI355X (gfx950)
// B=32, L=512, DIM=256, NH=4, HD=64.  SCALE = 8.
//
// Pipeline (5 kernels):
//  prep     : x,w_qkv -> bf16; w_proj -> [hi|hi|lo]; adj -> row bitsets
//  maskf    : in-block ballot bit-transpose + chunk-parallel mask23
//             (grid (32,8) = 256 blocks; maskA1 from qc==0 blocks)
//  gemm_qkv : qkv = x @ w_qkv^T via global_load_lds staging, scatter
//  attn     : barrier-free flash attn v8 (no max-tracking, gload_lds staging,
//             wave-private LDS P-relayout, mask prefetch)
//  gemm_out : out = ctx @ wproj_aug^T (global_load_lds, k>=512 wrap)
// ---------------------------------------------------------------------------

typedef unsigned long long u64;
typedef unsigned short u16;
typedef short bf16x8 __attribute__((ext_vector_type(8)));
typedef float f32x4 __attribute__((ext_vector_type(4)));

#define MFMA16(a, b, c) __builtin_amdgcn_mfma_f32_16x16x32_bf16((a), (b), (c), 0, 0, 0)

__device__ __forceinline__ unsigned f2bf(float f) {           // f32 -> bf16 (RNE)
  unsigned u = __float_as_uint(f);
  return (u + 0x7FFFu + ((u >> 16) & 1u)) >> 16;
}
__device__ __forceinline__ float bf2f(unsigned b) { return __uint_as_float(b << 16); }

// v_cvt_pk_bf16_f32: dst.lo = bf16(lo), dst.hi = bf16(hi)  (RNE)
__device__ __forceinline__ unsigned cvtpk(float lo, float hi) {
  unsigned r;
  asm("v_cvt_pk_bf16_f32 %0, %1, %2" : "=v"(r) : "v"(lo), "v"(hi));
  return r;
}

// async global -> LDS, 16B per lane.  LDS dest = wave-uniform base + lane*16
// (linear); swizzle is applied on the per-lane GLOBAL source + on LDS reads.
__device__ __forceinline__ void gload16(const u16* src, u16* ldsDst) {
  __builtin_amdgcn_global_load_lds(
      (const __attribute__((address_space(1))) void*)src,
      (__attribute__((address_space(3))) void*)ldsDst, 16, 0, 0);
}

// XOR bank swizzles: flip 16B-chunk bits (3..5 of elem offset) with row&7.
__device__ __forceinline__ int swzE(int row, int e) {
  return row * 64 + (e ^ ((row & 7) << 3));
}
__device__ __forceinline__ int swzV(int row, int c) {
  return row * 512 + (c ^ ((row & 7) << 3));
}

// ---- workspace layout (bytes) ---------------------------------------------
#define OFF_XB    ((size_t)0)          // x bf16        [16384][256]   8,388,608
#define OFF_WQKV  ((size_t)8388608)    // w_qkv bf16    [768][256]       393,216
#define OFF_WPA   ((size_t)8781824)    // w_proj aug    [256][768]       393,216
#define OFF_QB    ((size_t)9175040)    // q bf16        [32][4][512][64] 8,388,608
#define OFF_KB    ((size_t)17563648)   // k bf16        [32][4][512][64] 8,388,608
#define OFF_VTB   ((size_t)25952256)   // vT bf16       [32][4][64][512] 8,388,608
#define OFF_CTXA  ((size_t)34340864)   // ctx [hi|lo]   [16384][512]    16,777,216
#define OFF_ROWR  ((size_t)51118080)   // row bitsets   [32][512][8]u64  1,048,576
#define OFF_COLR  ((size_t)52166656)   // (spare)                        1,048,576
#define OFF_MASK  ((size_t)53215232)   // maskA[4][32][512][8]u64        4,194,304
// total 57,409,536 B (~54.8 MB)

// ---------------------------------------------------------------------------
// Fused prep: blk<1024 x->bf16; 1024..1071 w_qkv->bf16; 1072..1199 w_proj aug;
// 1200..3247 adj bitpack (+maskA0).  All 512-thread blocks.
__global__ __launch_bounds__(512) void prep(const float* __restrict__ x, u16* __restrict__ xb,
                                            const float* __restrict__ wqkv, u16* __restrict__ wqkvb,
                                            const float* __restrict__ wp, u16* __restrict__ wpa,
                                            const int* __restrict__ adj, u64* __restrict__ rowraw,
                                            u64* __restrict__ maskA0) {
  int blk = blockIdx.x;
  if (blk < 1072) {
    const float* src = (blk < 1024) ? x : wqkv;
    u16* dst = (blk < 1024) ? xb : wqkvb;
    int bb = (blk < 1024) ? blk : (blk - 1024);
    size_t i = ((size_t)bb * 512 + threadIdx.x) * 8;
    float4 a = *(const float4*)(src + i);
    float4 c = *(const float4*)(src + i + 4);
    uint4 o;
    o.x = f2bf(a.x) | (f2bf(a.y) << 16);
    o.y = f2bf(a.z) | (f2bf(a.w) << 16);
    o.z = f2bf(c.x) | (f2bf(c.y) << 16);
    o.w = f2bf(c.z) | (f2bf(c.w) << 16);
    *(uint4*)(dst + i) = o;
  } else if (blk < 1200) {
    int idx = (blk - 1072) * 512 + threadIdx.x;   // 0..65535
    int n = idx >> 8, k = idx & 255;
    float v = wp[idx];
    unsigned hi = f2bf(v);
    unsigned lo = f2bf(v - bf2f(hi));
    size_t base = (size_t)n * 768;
    wpa[base + k]       = (u16)hi;
    wpa[base + 256 + k] = (u16)hi;
    wpa[base + 512 + k] = (u16)lo;
  } else {
    int blk2 = blk - 1200;                // 64 blocks per batch b
    int b = blk2 >> 6, r0 = (blk2 & 63) * 8;
    int wave = threadIdx.x >> 6, lane = threadIdx.x & 63;
    #pragma unroll
    for (int rr = 0; rr < 8; ++rr) {
      int row = r0 + rr;
      int v = adj[((size_t)b * 512 + row) * 512 + wave * 64 + lane];
      u64 bal = __ballot(v == 1 || v >= 9);
      if (lane == 0) {
        size_t o = ((size_t)b * 512 + row) * 8 + wave;
        rowraw[o] = bal;
        maskA0[o] = bal | (((row >> 6) == wave) ? (1ull << (row & 63)) : 0ull);
      }
    }
  }
}

// ---------------------------------------------------------------------------
// maskf: per-(batch, q-chunk) block, 512 threads, grid (32, 8) = 256 blocks.
// Stage rowraw in BOTH layouts (btr [word][row] for ballots, rbm row-major
// padded for the reduction); in-block ballot bit-transpose -> cbuf (colraw,
// LDS-only; qc==0 blocks also write maskA1); then chunk-parallel mask23:
// thread (ql=tid>>3, wg=tid&7) ORs over its 64-column chunk with an EXACT
// saturation early-exit at cc=32, butterfly-combines across the 8-lane group.
__global__ __launch_bounds__(512) void maskf(const u64* __restrict__ rowraw,
                                             u64* __restrict__ maskA1,
                                             u64* __restrict__ maskA2,
                                             u64* __restrict__ maskA3) {
  __shared__ u64 btr[8 * 512];    // [word][row]
  __shared__ u64 rbm[4104];       // row-major rowraw, idx(c,w) = c*8+w+(c>>6)
  __shared__ u64 cbuf[4104];      // row-major colraw, same idx
  const int b = blockIdx.x, qc = blockIdx.y, tid = threadIdx.x;
  {
    const u64* src = rowraw + (size_t)b * 4096 + (size_t)tid * 8;
    u64 r[8];
    #pragma unroll
    for (int w = 0; w < 8; ++w) r[w] = src[w];
    #pragma unroll
    for (int w = 0; w < 8; ++w) btr[w * 512 + tid] = r[w];
    int li = tid * 8 + (tid >> 6);
    #pragma unroll
    for (int w = 0; w < 8; ++w) rbm[li + w] = r[w];
  }
  __syncthreads();
  {
    int w = tid >> 6, lane = tid & 63;    // wave w -> cols w*64 .. w*64+63
    u64 words[8];
    #pragma unroll
    for (int wd = 0; wd < 8; ++wd) {
      u64 word = btr[w * 512 + wd * 64 + lane];   // rowraw[row=wd*64+lane], word w
      u64 mine = 0;
      #pragma unroll 1
      for (int c = 0; c < 64; ++c) {
        u64 bal = __ballot((word >> c) & 1ull);   // bit t = a[wd*64+t][w*64+c]
        if (lane == c) mine = bal;
      }
      words[wd] = mine;
    }
    int col = w * 64 + lane;
    int li = col * 8 + (col >> 6);
    #pragma unroll
    for (int wd = 0; wd < 8; ++wd) cbuf[li + wd] = words[wd];   // colraw, no eye
    if (qc == 0) {                                              // write maskA1 once
      words[w] |= (1ull << lane);
      u64* m1 = maskA1 + (size_t)b * 4096 + (size_t)col * 8;
      #pragma unroll
      for (int wd = 0; wd < 8; ++wd) m1[wd] = words[wd];
    }
  }
  __syncthreads();

  const int ql = tid >> 3, wg = tid & 7;
  const int q = qc * 64 + ql;
  const u64 myrow_w = rbm[q * 8 + wg + (q >> 6)];   // word wg of rowraw[q]
  const u64 mycol_w = cbuf[q * 8 + wg + (q >> 6)];  // word wg of colraw[q]

  u64 a2[8] = {0, 0, 0, 0, 0, 0, 0, 0}, a3[8] = {0, 0, 0, 0, 0, 0, 0, 0};
  for (int cc = 0; cc < 64; ++cc) {
    int base = (wg * 64 + cc) * 8 + wg;            // idx(c, 0), c = wg*64+cc
    u64 p3 = 0ull - ((myrow_w >> cc) & 1ull);
    u64 p2 = 0ull - ((mycol_w >> cc) & 1ull);
    #pragma unroll
    for (int w = 0; w < 8; ++w) {
      a3[w] |= cbuf[base + w] & p3;                // colraw[c]
      a2[w] |= rbm[base + w] & p2;                 // rowraw[c]
    }
    if (cc == 31) {                                // exact early exit: OR only grows
      u64 f = ~0ull;
      #pragma unroll
      for (int w = 0; w < 8; ++w) f &= (a2[w] & a3[w]);
      if (__all((int)(f == ~0ull))) break;
    }
  }

  // combine the 8 chunk-partials (aligned 8-lane group) via butterfly
  #pragma unroll
  for (int off = 1; off < 8; off <<= 1)
    #pragma unroll
    for (int w = 0; w < 8; ++w) {
      a2[w] |= __shfl_xor(a2[w], off);
      a3[w] |= __shfl_xor(a3[w], off);
    }

  // thread stores word wg of its q (coalesced across the 8-lane group)
  u64 eye = ((q >> 6) == wg) ? (1ull << (q & 63)) : 0ull;
  size_t o = (size_t)b * 4096 + (size_t)q * 8 + wg;
  maskA2[o] = a2[wg] | eye;
  maskA3[o] = a3[wg] | eye;
}

// ---------------------------------------------------------------------------
// QKV GEMM: qkv = x @ w_qkv^T.  128x128 tile, BK=64, 4 k-steps, 4 waves 2x2.
// global_load_lds width 16, linear LDS dest, inverse-swizzled global source.
__global__ __launch_bounds__(256) void gemm_qkv(const u16* __restrict__ A,
                                                const u16* __restrict__ Bw,
                                                u16* __restrict__ o_q, u16* __restrict__ o_k,
                                                u16* __restrict__ o_v) {
  __shared__ u16 As[128 * 64];
  __shared__ u16 Bs[128 * 64];
  const int lin = blockIdx.x;
  const int logical = (lin & 7) * 96 + (lin >> 3);   // 768%8==0 -> bijective
  const int m0 = (logical / 6) * 128, n0 = (logical % 6) * 128;
  const int tid = threadIdx.x;
  const int lane = tid & 63, wid = tid >> 6;
  const int lg = lane >> 4, lc = lane & 15;
  const int wm = wid >> 1, wn = wid & 1;
  f32x4 acc[4][4] = {};

  const int srow = lane >> 3;                        // 0..7 within 8-row slab
  const int schunk = ((lane & 7) ^ srow) * 8;        // inverse swizzle
  #define STAGE_QKV(ks)                                                        \
    {                                                                          \
      int kk0 = (ks) * 64;                                                     \
      _Pragma("unroll")                                                        \
      for (int j = 0; j < 4; ++j) {                                            \
        int slab = wid * 4 + j;                                                \
        int r = slab * 8 + srow;                                               \
        gload16(A + (size_t)(m0 + r) * 256 + kk0 + schunk, &As[slab * 512]);   \
        gload16(Bw + (size_t)(n0 + r) * 256 + kk0 + schunk, &Bs[slab * 512]);  \
      }                                                                        \
    }

  STAGE_QKV(0);
  for (int ks = 0; ks < 4; ++ks) {
    __syncthreads();                   // vmcnt drained -> tile ks in LDS
    bf16x8 af[2][4], bf[2][4];
    #pragma unroll
    for (int kk = 0; kk < 2; ++kk)
      #pragma unroll
      for (int mi = 0; mi < 4; ++mi) {
        af[kk][mi] = *(const bf16x8*)&As[swzE(wm * 64 + mi * 16 + lc, kk * 32 + lg * 8)];
        bf[kk][mi] = *(const bf16x8*)&Bs[swzE(wn * 64 + mi * 16 + lc, kk * 32 + lg * 8)];
      }
    __syncthreads();                   // all waves done reading LDS
    if (ks < 3) STAGE_QKV(ks + 1);     // async loads overlap the MFMA block
    #pragma unroll
    for (int kk = 0; kk < 2; ++kk)
      #pragma unroll
      for (int mi = 0; mi < 4; ++mi)
        #pragma unroll
        for (int ni = 0; ni < 4; ++ni)
          acc[mi][ni] = MFMA16(af[kk][mi], bf[kk][ni], acc[mi][ni]);
  }
  #undef STAGE_QKV

  // scatter epilogue -> q[b][h][l][d], k[b][h][l][d], vT[b][h][d][l]
  #pragma unroll
  for (int mi = 0; mi < 4; ++mi) {
    int mbase = m0 + wm * 64 + mi * 16 + lg * 4;
    int bb = mbase >> 9, l = mbase & 511;
    #pragma unroll
    for (int ni = 0; ni < 4; ++ni) {
      int n = n0 + wn * 64 + ni * 16 + lc;
      if (n < 512) {   // uniform within each 16-lane group
        u16* dst = (n < 256) ? o_q : o_k;
        int c = n & 255, hh = c >> 6, dd = c & 63;
        size_t base = (((size_t)bb * 4 + hh) * 512 + l) * 64 + dd;
        #pragma unroll
        for (int r = 0; r < 4; ++r) dst[base + (size_t)r * 64] = (u16)f2bf(acc[mi][ni][r]);
      } else {         // V transposed per head: vT[b][h][d][l]
        int c = n - 512, hh = c >> 6, dd = c & 63;
        ushort4 pk;
        pk.x = (u16)f2bf(acc[mi][ni][0]); pk.y = (u16)f2bf(acc[mi][ni][1]);
        pk.z = (u16)f2bf(acc[mi][ni][2]); pk.w = (u16)f2bf(acc[mi][ni][3]);
        *(ushort4*)&o_v[(((size_t)bb * 4 + hh) * 64 + dd) * 512 + l] = pk;
      }
    }
  }
}

// ---------------------------------------------------------------------------
// Out-projection GEMM: 64x128 tile, BK=64, 12 k-steps, grid 512, XCD-chunked.
__global__ __launch_bounds__(256) void gemm_out(const u16* __restrict__ A,
                                                const u16* __restrict__ Bw,
                                                float* __restrict__ o_f) {
  __shared__ u16 As[64 * 64];
  __shared__ u16 Bs[128 * 64];
  const int lin = blockIdx.x;
  const int logical = (lin & 7) * 64 + (lin >> 3);   // 512%8==0 -> bijective
  const int m0 = (logical >> 1) * 64, n0 = (logical & 1) * 128;
  const int tid = threadIdx.x;
  const int lane = tid & 63, wid = tid >> 6;
  const int lg = lane >> 4, lc = lane & 15;
  const int wm = wid >> 1, wn = wid & 1;
  f32x4 acc[2][4] = {};

  const int srow = lane >> 3;
  const int schunk = ((lane & 7) ^ srow) * 8;
  #define STAGE_OUT(ks)                                                        \
    {                                                                          \
      int k0 = (ks) * 64;                                                      \
      int ka0 = (k0 >= 512) ? k0 - 512 : k0;                                   \
      _Pragma("unroll")                                                        \
      for (int j = 0; j < 2; ++j) {                                            \
        int slab = wid * 2 + j;                                                \
        int r = slab * 8 + srow;                                               \
        gload16(A + (size_t)(m0 + r) * 512 + ka0 + schunk, &As[slab * 512]);   \
      }                                                                        \
      _Pragma("unroll")                                                        \
      for (int j = 0; j < 4; ++j) {                                            \
        int slab = wid * 4 + j;                                                \
        int r = slab * 8 + srow;                                               \
        gload16(Bw + (size_t)(n0 + r) * 768 + k0 + schunk, &Bs[slab * 512]);   \
      }                                                                        \
    }

  STAGE_OUT(0);
  for (int ks = 0; ks < 12; ++ks) {
    __syncthreads();
    bf16x8 af[2][2], bf[2][4];
    #pragma unroll
    for (int kk = 0; kk < 2; ++kk) {
      #pragma unroll
      for (int mi = 0; mi < 2; ++mi)
        af[kk][mi] = *(const bf16x8*)&As[swzE(wm * 32 + mi * 16 + lc, kk * 32 + lg * 8)];
      #pragma unroll
      for (int ni = 0; ni < 4; ++ni)
        bf[kk][ni] = *(const bf16x8*)&Bs[swzE(wn * 64 + ni * 16 + lc, kk * 32 + lg * 8)];
    }
    __syncthreads();
    if (ks < 11) STAGE_OUT(ks + 1);
    #pragma unroll
    for (int kk = 0; kk < 2; ++kk)
      #pragma unroll
      for (int mi = 0; mi < 2; ++mi)
        #pragma unroll
        for (int ni = 0; ni < 4; ++ni)
          acc[mi][ni] = MFMA16(af[kk][mi], bf[kk][ni], acc[mi][ni]);
  }
  #undef STAGE_OUT

  #pragma unroll
  for (int mi = 0; mi < 2; ++mi) {
    int mbase = m0 + wm * 32 + mi * 16 + lg * 4;
    #pragma unroll
    for (int ni = 0; ni < 4; ++ni) {
      int n = n0 + wn * 64 + ni * 16 + lc;
      #pragma unroll
      for (int r = 0; r < 4; ++r) o_f[(size_t)(mbase + r) * 256 + n] = acc[mi][ni][r];
    }
  }
}

// ---------------------------------------------------------------------------
// P-step v8: no max-tracking (shift-invariant; scores provably small).
// Masked -> 0.  Per-lane partial row-sum in lrun (reduced in epilogue).
// Relayout C/D -> A-frag through the wave-private LDS buffer PsW:
// 4 x ds_write_b64 (P^T[q=lc][k]) then 2 x ds_read_b128.  DS ops are
// per-wave in-order -> no barrier, and sequential A/B reuse is WAR-safe.
__device__ __forceinline__ void p_step(const f32x4 sT[4], u64 mw, int lane, u16* PsW,
                                       float& lrun, bf16x8& ap0, bf16x8& ap1) {
  const float SC = 0.125f * 1.4426950408889634f;   // /sqrt(64) * log2(e)
  const int lg = lane >> 4, lc = lane & 15;
  float p[4][4];
  float ps = 0.f;
  #pragma unroll
  for (int nf = 0; nf < 4; ++nf)
    #pragma unroll
    for (int r = 0; r < 4; ++r) {
      bool ok = (mw >> (nf * 16 + r)) & 1ull;
      float e = __builtin_amdgcn_exp2f(sT[nf][r] * SC);
      e = ok ? e : 0.f;
      p[nf][r] = e;
      ps += e;
    }
  lrun += ps;

  #pragma unroll
  for (int nf = 0; nf < 4; ++nf) {
    uint2 w2;
    w2.x = cvtpk(p[nf][0], p[nf][1]);
    w2.y = cvtpk(p[nf][2], p[nf][3]);
    *(uint2*)&PsW[swzE(lc, nf * 16 + lg * 4)] = w2;   // keys nf*16+lg*4+0..3
  }
  ap0 = *(const bf16x8*)&PsW[swzE(lc, lg * 8)];
  ap1 = *(const bf16x8*)&PsW[swzE(lc, lg * 8 + 32)];
}

// ---------------------------------------------------------------------------
// Flash attention v8 — barrier-free, dual q-group, no max-tracking.
// Grid 256 (XCD-chunked), block = 512 threads (8 waves), 256 q-rows/block.
// K/V staged via global_load_lds (inverse-swizzled source, linear LDS dest).
// LDS: 64 (K) + 64 (V) + 16 (Ps) = 144 KB -> 1 block/CU, 8 waves.
__global__ __launch_bounds__(512, 1) void attn(const u16* __restrict__ qb, const u16* __restrict__ kb,
                                               const u16* __restrict__ vtb, const u64* __restrict__ maskA,
                                               u16* __restrict__ ctxa) {
  __shared__ u16 Ks[512 * 64];   // 64 KB, swzE
  __shared__ u16 Vs[64 * 512];   // 64 KB, swzV
  __shared__ u16 Ps[8][16 * 64]; // 16 KB, wave-private P relayout buffers
  const int lin = blockIdx.x;
  const int logical = (lin & 7) * 32 + (lin >> 3);   // lin%8 = XCD; bijective
  const int bh = logical >> 1, half = logical & 1;
  const int b = bh >> 2, h = bh & 3;
  const int tid = threadIdx.x, lane = tid & 63, wid = tid >> 6;   // wid 0..7
  const int lg = lane >> 4, lc = lane & 15;

  // ---- stage K [512][64] and V^T [64][512] via global_load_lds ----
  {
    const u16* kgs = kb + (size_t)bh * 512 * 64;
    const u16* vgs = vtb + (size_t)bh * 64 * 512;
    const int srow = lane >> 3;                    // K: 8 rows/slab, 8 lanes/row
    const int schunk = ((lane & 7) ^ srow) * 8;    // inverse swzE
    #pragma unroll
    for (int j = 0; j < 8; ++j) {
      int slab = wid * 8 + j;                      // 64 slabs
      gload16(kgs + (size_t)(slab * 8 + srow) * 64 + schunk, &Ks[slab * 512]);
    }
    #pragma unroll
    for (int j = 0; j < 8; ++j) {
      int vr = wid * 8 + j;                        // 64 V rows, 1 row/wave-inst
      gload16(vgs + (size_t)vr * 512 + ((lane ^ (vr & 7)) * 8), &Vs[vr * 512]);
    }
  }

  // Q as B-frag (col = q = lc, inner = d): two 16-row groups per wave
  const int qrow0 = half * 256 + wid * 32;
  const u16* qgA = qb + ((size_t)bh * 512 + qrow0 + lc) * 64;
  const u16* qgB = qgA + 16 * 64;
  bf16x8 qA0 = *(const bf16x8*)(qgA + lg * 8);
  bf16x8 qA1 = *(const bf16x8*)(qgA + 32 + lg * 8);
  bf16x8 qB0 = *(const bf16x8*)(qgB + lg * 8);
  bf16x8 qB1 = *(const bf16x8*)(qgB + 32 + lg * 8);

  float lrunA = 0.f, lrunB = 0.f;
  f32x4 accoA[4] = {}, accoB[4] = {};
  const u64* mrowA = maskA + ((size_t)(h * 32 + b) * 512 + qrow0 + lc) * 8;
  const u64* mrowB = mrowA + 16 * 8;
  u16* PsW = Ps[wid];

  u64 mwA = mrowA[0], mwB = mrowB[0];   // mask prefetch depth-1

  __syncthreads();   // staging visible; the ONLY block-wide sync

  for (int kt = 0; kt < 8; ++kt) {
    u64 nmwA = (kt < 7) ? mrowA[kt + 1] : 0ull;   // prefetch next tile's masks
    u64 nmwB = (kt < 7) ? mrowB[kt + 1] : 0ull;

    f32x4 sA[4], sB[4];
    __builtin_amdgcn_s_setprio(1);
    #pragma unroll
    for (int nf = 0; nf < 4; ++nf) {
      bf16x8 ak0 = *(const bf16x8*)&Ks[swzE(kt * 64 + nf * 16 + lc, lg * 8)];
      bf16x8 ak1 = *(const bf16x8*)&Ks[swzE(kt * 64 + nf * 16 + lc, lg * 8 + 32)];
      f32x4 zA = {0.f, 0.f, 0.f, 0.f};
      zA = MFMA16(ak0, qA0, zA);
      zA = MFMA16(ak1, qA1, zA);
      sA[nf] = zA;
      f32x4 zB = {0.f, 0.f, 0.f, 0.f};
      zB = MFMA16(ak0, qB0, zB);
      zB = MFMA16(ak1, qB1, zB);
      sB[nf] = zB;
    }
    __builtin_amdgcn_s_setprio(0);

    bf16x8 apA0, apA1, apB0, apB1;
    p_step(sA, mwA >> (lg * 4), lane, PsW, lrunA, apA0, apA1);
    p_step(sB, mwB >> (lg * 4), lane, PsW, lrunB, apB0, apB1);

    __builtin_amdgcn_s_setprio(1);
    #pragma unroll
    for (int df = 0; df < 4; ++df) {
      bf16x8 bv0 = *(const bf16x8*)&Vs[swzV(df * 16 + lc, kt * 64 + lg * 8)];
      bf16x8 bv1 = *(const bf16x8*)&Vs[swzV(df * 16 + lc, kt * 64 + 32 + lg * 8)];
      accoA[df] = MFMA16(apA0, bv0, accoA[df]);
      accoA[df] = MFMA16(apA1, bv1, accoA[df]);
      accoB[df] = MFMA16(apB0, bv0, accoB[df]);
      accoB[df] = MFMA16(apB1, bv1, accoB[df]);
    }
    __builtin_amdgcn_s_setprio(0);

    mwA = nmwA;
    mwB = nmwB;
  }

  // epilogue: reduce per-lane partial sums across the 4 lane-groups, then
  // normalize.  r outer / df inner (write-combine friendly), both groups.
  lrunA += __shfl_xor(lrunA, 16);
  lrunA += __shfl_xor(lrunA, 32);
  lrunB += __shfl_xor(lrunB, 16);
  lrunB += __shfl_xor(lrunB, 32);
  float lrA[4], lrB[4];
  #pragma unroll
  for (int r = 0; r < 4; ++r) {
    lrA[r] = 1.0f / __shfl(lrunA, (lane & 48) | (lg * 4 + r));
    lrB[r] = 1.0f / __shfl(lrunB, (lane & 48) | (lg * 4 + r));
  }
  #pragma unroll
  for (int r = 0; r < 4; ++r) {
    int rowq = qrow0 + lg * 4 + r;
    size_t baseA = ((size_t)b * 512 + rowq) * 512;
    size_t baseB = ((size_t)b * 512 + rowq + 16) * 512;
    #pragma unroll
    for (int df = 0; df < 4; ++df) {
      int c = h * 64 + df * 16 + lc;
      float vA = accoA[df][r] * lrA[r];
      unsigned hiA = f2bf(vA);
      ctxa[baseA + c]       = (u16)hiA;
      ctxa[baseA + 256 + c] = (u16)f2bf(vA - bf2f(hiA));
      float vB = accoB[df][r] * lrB[r];
      unsigned hiB = f2bf(vB);
      ctxa[baseB + c]       = (u16)hiB;
      ctxa[baseB + 256 + c] = (u16)f2bf(vB - bf2f(hiB));
    }
  }
}

// ---------------------------------------------------------------------------
extern "C" void kernel_launch(void* const* d_in, const int* in_sizes, int n_in,
                              void* d_out, int out_size, void* d_ws, size_t ws_size,
                              hipStream_t stream) {
  const float* x     = (const float*)d_in[0];
  const int*   adj   = (const int*)d_in[1];
  const float* wqkv  = (const float*)d_in[2];
  const float* wproj = (const float*)d_in[3];
  char* ws = (char*)d_ws;
  u16* xb     = (u16*)(ws + OFF_XB);
  u16* wqkvb  = (u16*)(ws + OFF_WQKV);
  u16* wpa    = (u16*)(ws + OFF_WPA);
  u16* qb     = (u16*)(ws + OFF_QB);
  u16* kb     = (u16*)(ws + OFF_KB);
  u16* vtb    = (u16*)(ws + OFF_VTB);
  u16* ctxa   = (u16*)(ws + OFF_CTXA);
  u64* rowraw = (u64*)(ws + OFF_ROWR);
  u64* maskA  = (u64*)(ws + OFF_MASK);
  const size_t MSTRIDE = (size_t)32 * 512 * 8;   // u64 elems per head-mask

  prep<<<dim3(3248), 512, 0, stream>>>(x, xb, wqkv, wqkvb, wproj, wpa, adj, rowraw, maskA);
  maskf<<<dim3(32, 8), 512, 0, stream>>>(rowraw, maskA + MSTRIDE, maskA + 2 * MSTRIDE, maskA + 3 * MSTRIDE);
  gemm_qkv<<<dim3(768), 256, 0, stream>>>(xb, wqkvb, qb, kb, vtb);
  attn<<<dim3(256), 512, 0, stream>>>(qb, kb, vtb, maskA, ctxa);
  gemm_out<<<dim3(512), 256, 0, stream>>>(ctxa, wpa, (float*)d_out);
}

// Round 19
// 85.958 us; speedup vs baseline: 1.3295x; 1.2480x over previous
//
#include <hip/hip_runtime.h>

// ---------------------------------------------------------------------------
// MultiHeadAttention with relational-adjacency mask, MI355X (gfx950)
// B=32, L=512, DIM=256, NH=4, HD=64.  SCALE = 8.
//
// Pipeline (6 kernels):
//  prep       : x,w_qkv -> bf16; w_proj -> [hi|hi|lo]; adj -> row bitsets
//  transposeW : colraw word wd for all cols via per-wave ballots; + maskA1
//  maskp      : maskA2/A3 via pairwise bitset intersection + ballot
//               (m3[q][j] = (rowq & rowj)!=0, m2[q][j] = (colq & colj)!=0)
//  gemm_qkv   : qkv = x @ w_qkv^T via global_load_lds staging, scatter
//  attn       : barrier-free flash attn v8 (no max-tracking, gload_lds
//               staging, wave-private LDS P-relayout, mask prefetch)
//  gemm_out   : out = ctx @ wproj_aug^T (global_load_lds, k>=512 wrap)
// ---------------------------------------------------------------------------

typedef unsigned long long u64;
typedef unsigned short u16;
typedef short bf16x8 __attribute__((ext_vector_type(8)));
typedef float f32x4 __attribute__((ext_vector_type(4)));

#define MFMA16(a, b, c) __builtin_amdgcn_mfma_f32_16x16x32_bf16((a), (b), (c), 0, 0, 0)

__device__ __forceinline__ unsigned f2bf(float f) {           // f32 -> bf16 (RNE)
  unsigned u = __float_as_uint(f);
  return (u + 0x7FFFu + ((u >> 16) & 1u)) >> 16;
}
__device__ __forceinline__ float bf2f(unsigned b) { return __uint_as_float(b << 16); }

// v_cvt_pk_bf16_f32: dst.lo = bf16(lo), dst.hi = bf16(hi)  (RNE)
__device__ __forceinline__ unsigned cvtpk(float lo, float hi) {
  unsigned r;
  asm("v_cvt_pk_bf16_f32 %0, %1, %2" : "=v"(r) : "v"(lo), "v"(hi));
  return r;
}

// async global -> LDS, 16B per lane.  LDS dest = wave-uniform base + lane*16
// (linear); swizzle is applied on the per-lane GLOBAL source + on LDS reads.
__device__ __forceinline__ void gload16(const u16* src, u16* ldsDst) {
  __builtin_amdgcn_global_load_lds(
      (const __attribute__((address_space(1))) void*)src,
      (__attribute__((address_space(3))) void*)ldsDst, 16, 0, 0);
}

// XOR bank swizzles: flip 16B-chunk bits (3..5 of elem offset) with row&7.
__device__ __forceinline__ int swzE(int row, int e) {
  return row * 64 + (e ^ ((row & 7) << 3));
}
__device__ __forceinline__ int swzV(int row, int c) {
  return row * 512 + (c ^ ((row & 7) << 3));
}

// ---- workspace layout (bytes) ---------------------------------------------
#define OFF_XB    ((size_t)0)          // x bf16        [16384][256]   8,388,608
#define OFF_WQKV  ((size_t)8388608)    // w_qkv bf16    [768][256]       393,216
#define OFF_WPA   ((size_t)8781824)    // w_proj aug    [256][768]       393,216
#define OFF_QB    ((size_t)9175040)    // q bf16        [32][4][512][64] 8,388,608
#define OFF_KB    ((size_t)17563648)   // k bf16        [32][4][512][64] 8,388,608
#define OFF_VTB   ((size_t)25952256)   // vT bf16       [32][4][64][512] 8,388,608
#define OFF_CTXA  ((size_t)34340864)   // ctx [hi|lo]   [16384][512]    16,777,216
#define OFF_ROWR  ((size_t)51118080)   // row bitsets   [32][512][8]u64  1,048,576
#define OFF_COLR  ((size_t)52166656)   // col bitsets   [32][512][8]u64  1,048,576
#define OFF_MASK  ((size_t)53215232)   // maskA[4][32][512][8]u64        4,194,304
// total 57,409,536 B (~54.8 MB)

// ---------------------------------------------------------------------------
// Fused prep: blk<1024 x->bf16; 1024..1071 w_qkv->bf16; 1072..1199 w_proj aug;
// 1200..3247 adj bitpack (+maskA0).  All 512-thread blocks.
__global__ __launch_bounds__(512) void prep(const float* __restrict__ x, u16* __restrict__ xb,
                                            const float* __restrict__ wqkv, u16* __restrict__ wqkvb,
                                            const float* __restrict__ wp, u16* __restrict__ wpa,
                                            const int* __restrict__ adj, u64* __restrict__ rowraw,
                                            u64* __restrict__ maskA0) {
  int blk = blockIdx.x;
  if (blk < 1072) {
    const float* src = (blk < 1024) ? x : wqkv;
    u16* dst = (blk < 1024) ? xb : wqkvb;
    int bb = (blk < 1024) ? blk : (blk - 1024);
    size_t i = ((size_t)bb * 512 + threadIdx.x) * 8;
    float4 a = *(const float4*)(src + i);
    float4 c = *(const float4*)(src + i + 4);
    uint4 o;
    o.x = f2bf(a.x) | (f2bf(a.y) << 16);
    o.y = f2bf(a.z) | (f2bf(a.w) << 16);
    o.z = f2bf(c.x) | (f2bf(c.y) << 16);
    o.w = f2bf(c.z) | (f2bf(c.w) << 16);
    *(uint4*)(dst + i) = o;
  } else if (blk < 1200) {
    int idx = (blk - 1072) * 512 + threadIdx.x;   // 0..65535
    int n = idx >> 8, k = idx & 255;
    float v = wp[idx];
    unsigned hi = f2bf(v);
    unsigned lo = f2bf(v - bf2f(hi));
    size_t base = (size_t)n * 768;
    wpa[base + k]       = (u16)hi;
    wpa[base + 256 + k] = (u16)hi;
    wpa[base + 512 + k] = (u16)lo;
  } else {
    int blk2 = blk - 1200;                // 64 blocks per batch b
    int b = blk2 >> 6, r0 = (blk2 & 63) * 8;
    int wave = threadIdx.x >> 6, lane = threadIdx.x & 63;
    #pragma unroll
    for (int rr = 0; rr < 8; ++rr) {
      int row = r0 + rr;
      int v = adj[((size_t)b * 512 + row) * 512 + wave * 64 + lane];
      u64 bal = __ballot(v == 1 || v >= 9);
      if (lane == 0) {
        size_t o = ((size_t)b * 512 + row) * 8 + wave;
        rowraw[o] = bal;
        maskA0[o] = bal | (((row >> 6) == wave) ? (1ull << (row & 63)) : 0ull);
      }
    }
  }
}

// ---------------------------------------------------------------------------
// transposeW: grid (32 b, 8 wd) x 512.  Block computes colraw word wd for all
// 512 cols.  Wave w covers cols w*64..w*64+63: lane t holds word w of row
// wd*64+t; 64 ballots produce one col-word each; lane t keeps col w*64+t's
// word.  Also writes maskA1 = colraw | eye.
__global__ __launch_bounds__(512) void transposeW(const u64* __restrict__ rowraw,
                                                  u64* __restrict__ colraw,
                                                  u64* __restrict__ maskA1) {
  const int b = blockIdx.x, wd = blockIdx.y;
  const int tid = threadIdx.x, w = tid >> 6, t = tid & 63;
  u64 rw = rowraw[(size_t)b * 4096 + (size_t)(wd * 64 + t) * 8 + w];
  u64 mine = 0;
  #pragma unroll 1
  for (int cbit = 0; cbit < 64; ++cbit) {
    u64 bal = __ballot((rw >> cbit) & 1ull);   // bit t = a[wd*64+t][w*64+cbit]
    if (t == cbit) mine = bal;
  }
  int col = w * 64 + t;
  size_t o = (size_t)b * 4096 + (size_t)col * 8 + wd;
  colraw[o] = mine;
  u64 eye = (w == wd) ? (1ull << t) : 0ull;    // col>>6 == w
  maskA1[o] = mine | eye;
}

// ---------------------------------------------------------------------------
// maskp: grid (32 b, 8 w, 2 type) x 512.  type 1 -> m3 (rowraw), 0 -> m2
// (colraw).  Block: stage the 512x8 bitsets (32KB, padded); lane j of wave
// holds bitset[w*64+j] in regs; per q (64 per wave): 8 broadcast LDS reads,
// AND/OR-tree, v_cmp_ne_u64, __ballot -> one 64-bit output word.
__global__ __launch_bounds__(512) void maskp(const u64* __restrict__ rowraw,
                                             const u64* __restrict__ colraw,
                                             u64* __restrict__ maskA2,
                                             u64* __restrict__ maskA3) {
  __shared__ u64 rows[512][9];   // +1 pad: jr loads spread banks
  const int b = blockIdx.x, w = blockIdx.y, type = blockIdx.z;
  const int tid = threadIdx.x, wavid = tid >> 6, lane = tid & 63;
  const u64* src = type ? rowraw : colraw;
  u64* dst = type ? maskA3 : maskA2;
  {
    const u64* s = src + (size_t)b * 4096 + (size_t)tid * 8;
    #pragma unroll
    for (int k = 0; k < 8; ++k) rows[tid][k] = s[k];
  }
  __syncthreads();
  u64 jr[8];
  #pragma unroll
  for (int k = 0; k < 8; ++k) jr[k] = rows[w * 64 + lane][k];
  #pragma unroll 4
  for (int qq = 0; qq < 64; ++qq) {
    int q = wavid * 64 + qq;
    u64 x = 0;
    #pragma unroll
    for (int k = 0; k < 8; ++k) x |= jr[k] & rows[q][k];   // broadcast reads
    u64 word = __ballot(x != 0ull);                        // bit j for col w*64+j
    if (lane == qq) {
      u64 eye = (wavid == w) ? (1ull << qq) : 0ull;        // q>>6 == w
      dst[(size_t)b * 4096 + (size_t)q * 8 + w] = word | eye;
    }
  }
}

// ---------------------------------------------------------------------------
// QKV GEMM: qkv = x @ w_qkv^T.  128x128 tile, BK=64, 4 k-steps, 4 waves 2x2.
// global_load_lds width 16, linear LDS dest, inverse-swizzled global source.
__global__ __launch_bounds__(256) void gemm_qkv(const u16* __restrict__ A,
                                                const u16* __restrict__ Bw,
                                                u16* __restrict__ o_q, u16* __restrict__ o_k,
                                                u16* __restrict__ o_v) {
  __shared__ u16 As[128 * 64];
  __shared__ u16 Bs[128 * 64];
  const int lin = blockIdx.x;
  const int logical = (lin & 7) * 96 + (lin >> 3);   // 768%8==0 -> bijective
  const int m0 = (logical / 6) * 128, n0 = (logical % 6) * 128;
  const int tid = threadIdx.x;
  const int lane = tid & 63, wid = tid >> 6;
  const int lg = lane >> 4, lc = lane & 15;
  const int wm = wid >> 1, wn = wid & 1;
  f32x4 acc[4][4] = {};

  const int srow = lane >> 3;                        // 0..7 within 8-row slab
  const int schunk = ((lane & 7) ^ srow) * 8;        // inverse swizzle
  #define STAGE_QKV(ks)                                                        \
    {                                                                          \
      int kk0 = (ks) * 64;                                                     \
      _Pragma("unroll")                                                        \
      for (int j = 0; j < 4; ++j) {                                            \
        int slab = wid * 4 + j;                                                \
        int r = slab * 8 + srow;                                               \
        gload16(A + (size_t)(m0 + r) * 256 + kk0 + schunk, &As[slab * 512]);   \
        gload16(Bw + (size_t)(n0 + r) * 256 + kk0 + schunk, &Bs[slab * 512]);  \
      }                                                                        \
    }

  STAGE_QKV(0);
  for (int ks = 0; ks < 4; ++ks) {
    __syncthreads();                   // vmcnt drained -> tile ks in LDS
    bf16x8 af[2][4], bf[2][4];
    #pragma unroll
    for (int kk = 0; kk < 2; ++kk)
      #pragma unroll
      for (int mi = 0; mi < 4; ++mi) {
        af[kk][mi] = *(const bf16x8*)&As[swzE(wm * 64 + mi * 16 + lc, kk * 32 + lg * 8)];
        bf[kk][mi] = *(const bf16x8*)&Bs[swzE(wn * 64 + mi * 16 + lc, kk * 32 + lg * 8)];
      }
    __syncthreads();                   // all waves done reading LDS
    if (ks < 3) STAGE_QKV(ks + 1);     // async loads overlap the MFMA block
    #pragma unroll
    for (int kk = 0; kk < 2; ++kk)
      #pragma unroll
      for (int mi = 0; mi < 4; ++mi)
        #pragma unroll
        for (int ni = 0; ni < 4; ++ni)
          acc[mi][ni] = MFMA16(af[kk][mi], bf[kk][ni], acc[mi][ni]);
  }
  #undef STAGE_QKV

  // scatter epilogue -> q[b][h][l][d], k[b][h][l][d], vT[b][h][d][l]
  #pragma unroll
  for (int mi = 0; mi < 4; ++mi) {
    int mbase = m0 + wm * 64 + mi * 16 + lg * 4;
    int bb = mbase >> 9, l = mbase & 511;
    #pragma unroll
    for (int ni = 0; ni < 4; ++ni) {
      int n = n0 + wn * 64 + ni * 16 + lc;
      if (n < 512) {   // uniform within each 16-lane group
        u16* dst = (n < 256) ? o_q : o_k;
        int c = n & 255, hh = c >> 6, dd = c & 63;
        size_t base = (((size_t)bb * 4 + hh) * 512 + l) * 64 + dd;
        #pragma unroll
        for (int r = 0; r < 4; ++r) dst[base + (size_t)r * 64] = (u16)f2bf(acc[mi][ni][r]);
      } else {         // V transposed per head: vT[b][h][d][l]
        int c = n - 512, hh = c >> 6, dd = c & 63;
        ushort4 pk;
        pk.x = (u16)f2bf(acc[mi][ni][0]); pk.y = (u16)f2bf(acc[mi][ni][1]);
        pk.z = (u16)f2bf(acc[mi][ni][2]); pk.w = (u16)f2bf(acc[mi][ni][3]);
        *(ushort4*)&o_v[(((size_t)bb * 4 + hh) * 64 + dd) * 512 + l] = pk;
      }
    }
  }
}

// ---------------------------------------------------------------------------
// Out-projection GEMM: 64x128 tile, BK=64, 12 k-steps, grid 512, XCD-chunked.
__global__ __launch_bounds__(256) void gemm_out(const u16* __restrict__ A,
                                                const u16* __restrict__ Bw,
                                                float* __restrict__ o_f) {
  __shared__ u16 As[64 * 64];
  __shared__ u16 Bs[128 * 64];
  const int lin = blockIdx.x;
  const int logical = (lin & 7) * 64 + (lin >> 3);   // 512%8==0 -> bijective
  const int m0 = (logical >> 1) * 64, n0 = (logical & 1) * 128;
  const int tid = threadIdx.x;
  const int lane = tid & 63, wid = tid >> 6;
  const int lg = lane >> 4, lc = lane & 15;
  const int wm = wid >> 1, wn = wid & 1;
  f32x4 acc[2][4] = {};

  const int srow = lane >> 3;
  const int schunk = ((lane & 7) ^ srow) * 8;
  #define STAGE_OUT(ks)                                                        \
    {                                                                          \
      int k0 = (ks) * 64;                                                      \
      int ka0 = (k0 >= 512) ? k0 - 512 : k0;                                   \
      _Pragma("unroll")                                                        \
      for (int j = 0; j < 2; ++j) {                                            \
        int slab = wid * 2 + j;                                                \
        int r = slab * 8 + srow;                                               \
        gload16(A + (size_t)(m0 + r) * 512 + ka0 + schunk, &As[slab * 512]);   \
      }                                                                        \
      _Pragma("unroll")                                                        \
      for (int j = 0; j < 4; ++j) {                                            \
        int slab = wid * 4 + j;                                                \
        int r = slab * 8 + srow;                                               \
        gload16(Bw + (size_t)(n0 + r) * 768 + k0 + schunk, &Bs[slab * 512]);   \
      }                                                                        \
    }

  STAGE_OUT(0);
  for (int ks = 0; ks < 12; ++ks) {
    __syncthreads();
    bf16x8 af[2][2], bf[2][4];
    #pragma unroll
    for (int kk = 0; kk < 2; ++kk) {
      #pragma unroll
      for (int mi = 0; mi < 2; ++mi)
        af[kk][mi] = *(const bf16x8*)&As[swzE(wm * 32 + mi * 16 + lc, kk * 32 + lg * 8)];
      #pragma unroll
      for (int ni = 0; ni < 4; ++ni)
        bf[kk][ni] = *(const bf16x8*)&Bs[swzE(wn * 64 + ni * 16 + lc, kk * 32 + lg * 8)];
    }
    __syncthreads();
    if (ks < 11) STAGE_OUT(ks + 1);
    #pragma unroll
    for (int kk = 0; kk < 2; ++kk)
      #pragma unroll
      for (int mi = 0; mi < 2; ++mi)
        #pragma unroll
        for (int ni = 0; ni < 4; ++ni)
          acc[mi][ni] = MFMA16(af[kk][mi], bf[kk][ni], acc[mi][ni]);
  }
  #undef STAGE_OUT

  #pragma unroll
  for (int mi = 0; mi < 2; ++mi) {
    int mbase = m0 + wm * 32 + mi * 16 + lg * 4;
    #pragma unroll
    for (int ni = 0; ni < 4; ++ni) {
      int n = n0 + wn * 64 + ni * 16 + lc;
      #pragma unroll
      for (int r = 0; r < 4; ++r) o_f[(size_t)(mbase + r) * 256 + n] = acc[mi][ni][r];
    }
  }
}

// ---------------------------------------------------------------------------
// P-step v8: no max-tracking (shift-invariant; scores provably small).
// Masked -> 0.  Per-lane partial row-sum in lrun (reduced in epilogue).
// Relayout C/D -> A-frag through the wave-private LDS buffer PsW:
// 4 x ds_write_b64 (P^T[q=lc][k]) then 2 x ds_read_b128.  DS ops are
// per-wave in-order -> no barrier, and sequential A/B reuse is WAR-safe.
__device__ __forceinline__ void p_step(const f32x4 sT[4], u64 mw, int lane, u16* PsW,
                                       float& lrun, bf16x8& ap0, bf16x8& ap1) {
  const float SC = 0.125f * 1.4426950408889634f;   // /sqrt(64) * log2(e)
  const int lg = lane >> 4, lc = lane & 15;
  float p[4][4];
  float ps = 0.f;
  #pragma unroll
  for (int nf = 0; nf < 4; ++nf)
    #pragma unroll
    for (int r = 0; r < 4; ++r) {
      bool ok = (mw >> (nf * 16 + r)) & 1ull;
      float e = __builtin_amdgcn_exp2f(sT[nf][r] * SC);
      e = ok ? e : 0.f;
      p[nf][r] = e;
      ps += e;
    }
  lrun += ps;

  #pragma unroll
  for (int nf = 0; nf < 4; ++nf) {
    uint2 w2;
    w2.x = cvtpk(p[nf][0], p[nf][1]);
    w2.y = cvtpk(p[nf][2], p[nf][3]);
    *(uint2*)&PsW[swzE(lc, nf * 16 + lg * 4)] = w2;   // keys nf*16+lg*4+0..3
  }
  ap0 = *(const bf16x8*)&PsW[swzE(lc, lg * 8)];
  ap1 = *(const bf16x8*)&PsW[swzE(lc, lg * 8 + 32)];
}

// ---------------------------------------------------------------------------
// Flash attention v8 — barrier-free, dual q-group, no max-tracking.
// Grid 256 (XCD-chunked), block = 512 threads (8 waves), 256 q-rows/block.
// K/V staged via global_load_lds (inverse-swizzled source, linear LDS dest).
// LDS: 64 (K) + 64 (V) + 16 (Ps) = 144 KB -> 1 block/CU, 8 waves.
__global__ __launch_bounds__(512, 1) void attn(const u16* __restrict__ qb, const u16* __restrict__ kb,
                                               const u16* __restrict__ vtb, const u64* __restrict__ maskA,
                                               u16* __restrict__ ctxa) {
  __shared__ u16 Ks[512 * 64];   // 64 KB, swzE
  __shared__ u16 Vs[64 * 512];   // 64 KB, swzV
  __shared__ u16 Ps[8][16 * 64]; // 16 KB, wave-private P relayout buffers
  const int lin = blockIdx.x;
  const int logical = (lin & 7) * 32 + (lin >> 3);   // lin%8 = XCD; bijective
  const int bh = logical >> 1, half = logical & 1;
  const int b = bh >> 2, h = bh & 3;
  const int tid = threadIdx.x, lane = tid & 63, wid = tid >> 6;   // wid 0..7
  const int lg = lane >> 4, lc = lane & 15;

  // ---- stage K [512][64] and V^T [64][512] via global_load_lds ----
  {
    const u16* kgs = kb + (size_t)bh * 512 * 64;
    const u16* vgs = vtb + (size_t)bh * 64 * 512;
    const int srow = lane >> 3;                    // K: 8 rows/slab, 8 lanes/row
    const int schunk = ((lane & 7) ^ srow) * 8;    // inverse swzE
    #pragma unroll
    for (int j = 0; j < 8; ++j) {
      int slab = wid * 8 + j;                      // 64 slabs
      gload16(kgs + (size_t)(slab * 8 + srow) * 64 + schunk, &Ks[slab * 512]);
    }
    #pragma unroll
    for (int j = 0; j < 8; ++j) {
      int vr = wid * 8 + j;                        // 64 V rows, 1 row/wave-inst
      gload16(vgs + (size_t)vr * 512 + ((lane ^ (vr & 7)) * 8), &Vs[vr * 512]);
    }
  }

  // Q as B-frag (col = q = lc, inner = d): two 16-row groups per wave
  const int qrow0 = half * 256 + wid * 32;
  const u16* qgA = qb + ((size_t)bh * 512 + qrow0 + lc) * 64;
  const u16* qgB = qgA + 16 * 64;
  bf16x8 qA0 = *(const bf16x8*)(qgA + lg * 8);
  bf16x8 qA1 = *(const bf16x8*)(qgA + 32 + lg * 8);
  bf16x8 qB0 = *(const bf16x8*)(qgB + lg * 8);
  bf16x8 qB1 = *(const bf16x8*)(qgB + 32 + lg * 8);

  float lrunA = 0.f, lrunB = 0.f;
  f32x4 accoA[4] = {}, accoB[4] = {};
  const u64* mrowA = maskA + ((size_t)(h * 32 + b) * 512 + qrow0 + lc) * 8;
  const u64* mrowB = mrowA + 16 * 8;
  u16* PsW = Ps[wid];

  u64 mwA = mrowA[0], mwB = mrowB[0];   // mask prefetch depth-1

  __syncthreads();   // staging visible; the ONLY block-wide sync

  for (int kt = 0; kt < 8; ++kt) {
    u64 nmwA = (kt < 7) ? mrowA[kt + 1] : 0ull;   // prefetch next tile's masks
    u64 nmwB = (kt < 7) ? mrowB[kt + 1] : 0ull;

    f32x4 sA[4], sB[4];
    __builtin_amdgcn_s_setprio(1);
    #pragma unroll
    for (int nf = 0; nf < 4; ++nf) {
      bf16x8 ak0 = *(const bf16x8*)&Ks[swzE(kt * 64 + nf * 16 + lc, lg * 8)];
      bf16x8 ak1 = *(const bf16x8*)&Ks[swzE(kt * 64 + nf * 16 + lc, lg * 8 + 32)];
      f32x4 zA = {0.f, 0.f, 0.f, 0.f};
      zA = MFMA16(ak0, qA0, zA);
      zA = MFMA16(ak1, qA1, zA);
      sA[nf] = zA;
      f32x4 zB = {0.f, 0.f, 0.f, 0.f};
      zB = MFMA16(ak0, qB0, zB);
      zB = MFMA16(ak1, qB1, zB);
      sB[nf] = zB;
    }
    __builtin_amdgcn_s_setprio(0);

    bf16x8 apA0, apA1, apB0, apB1;
    p_step(sA, mwA >> (lg * 4), lane, PsW, lrunA, apA0, apA1);
    p_step(sB, mwB >> (lg * 4), lane, PsW, lrunB, apB0, apB1);

    __builtin_amdgcn_s_setprio(1);
    #pragma unroll
    for (int df = 0; df < 4; ++df) {
      bf16x8 bv0 = *(const bf16x8*)&Vs[swzV(df * 16 + lc, kt * 64 + lg * 8)];
      bf16x8 bv1 = *(const bf16x8*)&Vs[swzV(df * 16 + lc, kt * 64 + 32 + lg * 8)];
      accoA[df] = MFMA16(apA0, bv0, accoA[df]);
      accoA[df] = MFMA16(apA1, bv1, accoA[df]);
      accoB[df] = MFMA16(apB0, bv0, accoB[df]);
      accoB[df] = MFMA16(apB1, bv1, accoB[df]);
    }
    __builtin_amdgcn_s_setprio(0);

    mwA = nmwA;
    mwB = nmwB;
  }

  // epilogue: reduce per-lane partial sums across the 4 lane-groups, then
  // normalize.  r outer / df inner (write-combine friendly), both groups.
  lrunA += __shfl_xor(lrunA, 16);
  lrunA += __shfl_xor(lrunA, 32);
  lrunB += __shfl_xor(lrunB, 16);
  lrunB += __shfl_xor(lrunB, 32);
  float lrA[4], lrB[4];
  #pragma unroll
  for (int r = 0; r < 4; ++r) {
    lrA[r] = 1.0f / __shfl(lrunA, (lane & 48) | (lg * 4 + r));
    lrB[r] = 1.0f / __shfl(lrunB, (lane & 48) | (lg * 4 + r));
  }
  #pragma unroll
  for (int r = 0; r < 4; ++r) {
    int rowq = qrow0 + lg * 4 + r;
    size_t baseA = ((size_t)b * 512 + rowq) * 512;
    size_t baseB = ((size_t)b * 512 + rowq + 16) * 512;
    #pragma unroll
    for (int df = 0; df < 4; ++df) {
      int c = h * 64 + df * 16 + lc;
      float vA = accoA[df][r] * lrA[r];
      unsigned hiA = f2bf(vA);
      ctxa[baseA + c]       = (u16)hiA;
      ctxa[baseA + 256 + c] = (u16)f2bf(vA - bf2f(hiA));
      float vB = accoB[df][r] * lrB[r];
      unsigned hiB = f2bf(vB);
      ctxa[baseB + c]       = (u16)hiB;
      ctxa[baseB + 256 + c] = (u16)f2bf(vB - bf2f(hiB));
    }
  }
}

// ---------------------------------------------------------------------------
extern "C" void kernel_launch(void* const* d_in, const int* in_sizes, int n_in,
                              void* d_out, int out_size, void* d_ws, size_t ws_size,
                              hipStream_t stream) {
  const float* x     = (const float*)d_in[0];
  const int*   adj   = (const int*)d_in[1];
  const float* wqkv  = (const float*)d_in[2];
  const float* wproj = (const float*)d_in[3];
  char* ws = (char*)d_ws;
  u16* xb     = (u16*)(ws + OFF_XB);
  u16* wqkvb  = (u16*)(ws + OFF_WQKV);
  u16* wpa    = (u16*)(ws + OFF_WPA);
  u16* qb     = (u16*)(ws + OFF_QB);
  u16* kb     = (u16*)(ws + OFF_KB);
  u16* vtb    = (u16*)(ws + OFF_VTB);
  u16* ctxa   = (u16*)(ws + OFF_CTXA);
  u64* rowraw = (u64*)(ws + OFF_ROWR);
  u64* colraw = (u64*)(ws + OFF_COLR);
  u64* maskA  = (u64*)(ws + OFF_MASK);
  const size_t MSTRIDE = (size_t)32 * 512 * 8;   // u64 elems per head-mask

  prep<<<dim3(3248), 512, 0, stream>>>(x, xb, wqkv, wqkvb, wproj, wpa, adj, rowraw, maskA);
  transposeW<<<dim3(32, 8), 512, 0, stream>>>(rowraw, colraw, maskA + MSTRIDE);
  maskp<<<dim3(32, 8, 2), 512, 0, stream>>>(rowraw, colraw, maskA + 2 * MSTRIDE, maskA + 3 * MSTRIDE);
  gemm_qkv<<<dim3(768), 256, 0, stream>>>(xb, wqkvb, qb, kb, vtb);
  attn<<<dim3(256), 512, 0, stream>>>(qb, kb, vtb, maskA, ctxa);
  gemm_out<<<dim3(512), 256, 0, stream>>>(ctxa, wpa, (float*)d_out);
}